// Round 8
// baseline (262.361 us; speedup 1.0000x reference)
//
#include <hip/hip_runtime.h>
#include <math.h>

#define DD 64
#define CC 128
#define HH 512
#define BATCH 4096

typedef __attribute__((ext_vector_type(2))) float f32x2;
typedef unsigned long long u64;

__device__ __forceinline__ f32x2 splat2(float x) { f32x2 v; v[0] = x; v[1] = x; return v; }

// packed FMA with the one legal scalar source: src0 is an SGPR pair {h,h}.
__device__ __forceinline__ f32x2 pk_fma_s(u64 hpair, f32x2 b, f32x2 c) {
    f32x2 d;
    asm("v_pk_fma_f32 %0, %1, %2, %3" : "=v"(d) : "s"(hpair), "v"(b), "v"(c));
    return d;
}

__device__ __forceinline__ float fast_softplus(float x) {
    float t = exp2f(-fabsf(x) * 1.44269504f);
    return fmaxf(x, 0.f) + 0.69314718f * log2f(1.f + t);
}

// broadcast lane l's value to an SGPR pair {x,x} for pk_fma_s
__device__ __forceinline__ u64 rl_pair(float x, int l) {
    unsigned u = (unsigned)__builtin_amdgcn_readlane(__float_as_int(x), l);
    return ((u64)u << 32) | u;
}

typedef const __attribute__((address_space(1))) void* as1_cptr;
typedef __attribute__((address_space(3))) void* as3_ptr;
__device__ __forceinline__ void glds16(const float* g, float* l) {
    __builtin_amdgcn_global_load_lds((as1_cptr)g, (as3_ptr)l, 16, 0, 0);
}

#define WAIT_VM(N) asm volatile("s_waitcnt vmcnt(" #N ")" ::: "memory")
#define LGKM0()    asm volatile("s_waitcnt lgkmcnt(0)" ::: "memory")
#define CFENCE()   asm volatile("" ::: "memory")

// R8: COLUMN-SPLIT decomposition. Elimination record R1-R7: VALU count, ds_read
// latency, TLP, staging drain all falsified; invariant binder = per-CU LDS
// READ VOLUME (each wave read the full 2KB of every W2 row; 8 waves/CU ->
// ~2000-2800cy of the 3840cy iteration on the shared LDS pipe; R3's 15%
// cross-block overlap and R4's exact saturation at 16 waves both fit).
//
// New layout: block = 4 waves x 8 batch rows; wave w owns hidden units
// [128w,128w+128), lane l units (128w+2l, +1) for ALL 8 rows (p1/p2 = f32x2[8],
// same state bytes as before). A wave reads 512B per W2 row (1 b64/lane)
// instead of 2KB -> ~4x less LDS read demand. h1/h2/z cross wave boundaries
// via small LDS tables (72/72/8 floats) + 3 barriers/iter.
// acc/z: wave w owns batch rows (2w, 2w+1), lane c cols (c, 64+c) as before.
// Staging: R7's proven 3-buffer counted-vmcnt machinery, now LINEAR layout.
__global__ __launch_bounds__(256, 2) void made_sample(
    const float* __restrict__ ctx,   // (B, C)
    const float* __restrict__ eps,   // (B, D)
    const float* __restrict__ W1,    // (D+C, H)
    const float* __restrict__ b1,    // (H)
    const float* __restrict__ W2,    // (H, H)
    const float* __restrict__ b2,    // (H)
    const float* __restrict__ W3,    // (H, 2D)
    const float* __restrict__ b3,    // (2D)
    float* __restrict__ out)         // (B, D)
{
    const int lane = threadIdx.x & 63;
    const int w    = threadIdx.x >> 6;       // wave 0..3
    const int blk8 = blockIdx.x * 8;         // 8 batch rows per block
    const int u0   = 128 * w + 2 * lane;     // owned unit pair (u0, u0+1)
    const int deg0 = (u0 % 63) + 1;
    const int deg1 = ((u0 + 1) % 63) + 1;
    const int t0   = u0 / 63;                // finalize-slot of u0 (exact when deg0==i)
    const int t1   = (u0 + 1) / 63;

    __shared__ float sbuf[3][10 * HH];       // 3 x 20KB: slots 0..8 W2 rows, slot 9 W1 row (LINEAR)
    __shared__ float w3sb[3][5 * 256];       // 3 x 5KB: 5 W3 pair slots
    __shared__ float h1t[128];               // h1[t*8+r], 72 used
    __shared__ float h2t[128];               // h2[t*8+r]
    __shared__ float zt[8];                  // z_i per batch row

    // LINEAR row staging: floats [0,256) then [256,512)
    auto stage_row = [&](const float* src, float* dst) {
        glds16(src + lane * 4,       dst);
        glds16(src + 256 + lane * 4, dst + 256);
    };
    auto stage_w3pair = [&](int k0, int k1, float* dst) {
        const float* g = (lane < 32) ? (W3 + k0 * (2 * DD) + lane * 4)
                                     : (W3 + k1 * (2 * DD) + (lane - 32) * 4);
        glds16(g, dst);
    };

    // per-lane state: unit-pair preactivations for all 8 rows
    f32x2 p1[8], p2[8];
    const f32x2 b1v = *(const f32x2*)(b1 + u0);
    const f32x2 b2v = *(const f32x2*)(b2 + u0);
    #pragma unroll
    for (int r = 0; r < 8; ++r) { p1[r] = b1v; p2[r] = b2v; }

    // output accumulators for rows (2w, 2w+1), lane c owns cols (c, 64+c)
    f32x2 accA[2], accB[2];
    accA[0] = splat2(0.f); accA[1] = splat2(0.f);
    accB[0] = splat2(0.f); accB[1] = splat2(0.f);

    float ca[8], cb[8];
    #pragma unroll
    for (int r = 0; r < 8; ++r) {
        ca[r] = ctx[(blk8 + r) * CC + lane];
        cb[r] = ctx[(blk8 + r) * CC + 64 + lane];
    }
    float ep[2];
    #pragma unroll
    for (int rr = 0; rr < 2; ++rr) ep[rr] = eps[(blk8 + 2 * w + rr) * DD + lane];
    const float b3m = b3[lane];
    const float b3p = b3[64 + lane];

    auto stage_ctx = [&](int ch, float* buf) {
        stage_row(W1 + (DD + 8 * ch + 2 * w) * HH,     buf + (2 * w) * HH);
        stage_row(W1 + (DD + 8 * ch + 2 * w + 1) * HH, buf + (2 * w + 1) * HH);
    };
    // UNIFORM glds count per wave: {7,7,6,5} (R7-proven)
    auto stage_step = [&](int in, float* buf, float* w3buf) {
        const int basen = (in == 0) ? 0 : (in - 1);
        const int r8 = (basen + 504 < HH) ? (basen + 504) : (HH - 1);
        stage_row(W2 + (basen + 63 * w) * HH,       buf + w * HH);
        stage_row(W2 + (basen + 63 * (4 + w)) * HH, buf + (4 + w) * HH);
        if (w == 0) stage_row(W2 + r8 * HH, buf + 8 * HH);
        if (w == 1) stage_row(W1 + in * HH, buf + 9 * HH);
        stage_w3pair(basen + 63 * (2 * w), basen + 63 * (2 * w + 1),
                     w3buf + w * 256);
        if (w == 2) stage_w3pair(r8, r8, w3buf + 4 * 256);
    };
    auto wait_step = [&]() {
        if (w == 0 || w == 1) WAIT_VM(7);
        else if (w == 2)      WAIT_VM(6);
        else                  WAIT_VM(5);
    };

    // ---- context init: p1 += ctx @ W1[D:,:], col-split consume ----
    stage_ctx(0, sbuf[0]);
    stage_ctx(1, sbuf[1]);
    int bc = 0;
    #pragma unroll 1
    for (int ch = 0; ch < 16; ++ch) {
        if (ch < 15) WAIT_VM(4); else WAIT_VM(0);
        __builtin_amdgcn_s_barrier();
        CFENCE();
        __builtin_amdgcn_sched_barrier(0);
        const int b2i = (bc < 1) ? bc + 2 : bc - 1;
        if (ch < 14) stage_ctx(ch + 2, sbuf[b2i]);
        float* cur = sbuf[bc];
        #pragma unroll
        for (int q = 0; q < 8; ++q) {
            const f32x2 wv = *(const f32x2*)(cur + q * HH + u0);  // W1[D+8ch+q, u0..]
            const int c = 8 * ch + q;
            #pragma unroll
            for (int r = 0; r < 8; ++r) {
                const u64 cv = rl_pair((ch < 8) ? ca[r] : cb[r], c & 63);
                p1[r] = pk_fma_s(cv, wv, p1[r]);
            }
        }
        bc = (bc < 2) ? bc + 1 : 0;
    }
    __syncthreads();                              // full drain before re-staging

    float zk[2] = {0.f, 0.f};
    stage_step(0, sbuf[0], w3sb[0]);
    stage_step(1, sbuf[1], w3sb[1]);
    bc = 0;
    f32x2 w1v = splat2(0.f);   // W1 row-i unit-pair: read at iter i, used at i+1

    // ---- autoregressive main loop: 3 phases, 3 barriers ----
    #pragma unroll 1
    for (int i = 0; i < DD; ++i) {
        // boundary: buf-i staged; zt(i-1) + h-tables quiesced; buf(i-1) free
        if (i < 63) wait_step(); else WAIT_VM(0);
        LGKM0();
        __builtin_amdgcn_s_barrier();
        CFENCE();
        __builtin_amdgcn_sched_barrier(0);

        float* cur = sbuf[bc];
        const float* w3s = w3sb[bc];
        const int b2i = (bc < 1) ? bc + 2 : bc - 1;
        if (i < 62) stage_step(i + 2, sbuf[b2i], w3sb[b2i]);

        const bool h9 = (i >= 1) && (i - 1 < 8);  // 9th finalizing unit exists

        // -- phase A: z_{i-1} feedback into p1; select+publish h1 (deg==i) --
        if (i > 0) {
            const float zv = zt[lane & 7];        // broadcast-ish b32
            #pragma unroll
            for (int r = 0; r < 8; ++r) {
                const u64 zp = rl_pair(zv, r);
                p1[r] = pk_fma_s(zp, w1v, p1[r]);
            }
            if (deg0 == i) {
                #pragma unroll
                for (int r = 0; r < 8; ++r) h1t[t0 * 8 + r] = fmaxf(p1[r][0], 0.f);
            }
            if (deg1 == i) {
                #pragma unroll
                for (int r = 0; r < 8; ++r) h1t[t1 * 8 + r] = fmaxf(p1[r][1], 0.f);
            }
        }
        LGKM0();
        __builtin_amdgcn_s_barrier();             // B1: h1 table ready
        CFENCE();

        // -- phase B: rank-9 update of p2 slice; select+publish h2 (deg==i) --
        w1v = *(const f32x2*)(cur + 9 * HH + u0); // W1 row i pair, for iter i+1
        if (i > 0) {
            const float hv0 = h1t[lane];          // h1[0..63]
            const float hv1 = h1t[64 + lane];     // h1[64..71] (t=8)
            #pragma unroll
            for (int t = 0; t < 8; ++t) {
                const f32x2 wv = *(const f32x2*)(cur + t * HH + u0);
                #pragma unroll
                for (int r = 0; r < 8; ++r) {
                    const u64 hp = rl_pair(hv0, t * 8 + r);
                    p2[r] = pk_fma_s(hp, wv, p2[r]);
                }
            }
            if (h9) {
                const f32x2 wv = *(const f32x2*)(cur + 8 * HH + u0);
                #pragma unroll
                for (int r = 0; r < 8; ++r) {
                    const u64 hp = rl_pair(hv1, r);   // idx 64+r
                    p2[r] = pk_fma_s(hp, wv, p2[r]);
                }
            }
            if (deg0 == i) {
                #pragma unroll
                for (int r = 0; r < 8; ++r) h2t[t0 * 8 + r] = fmaxf(p2[r][0], 0.f);
            }
            if (deg1 == i) {
                #pragma unroll
                for (int r = 0; r < 8; ++r) h2t[t1 * 8 + r] = fmaxf(p2[r][1], 0.f);
            }
        }
        LGKM0();
        __builtin_amdgcn_s_barrier();             // B2: h2 table ready
        CFENCE();

        // -- phase C: output accumulation (own 2 rows) + z_i publish --
        if (i > 0) {
            const float gv0 = h2t[lane];
            const float gv1 = h2t[64 + lane];
            const int row0 = 2 * w, row1 = 2 * w + 1;
            #pragma unroll
            for (int t = 0; t < 8; ++t) {
                f32x2 w3v;
                w3v[0] = w3s[t * 128 + lane];         // W3[k_t, lane]
                w3v[1] = w3s[t * 128 + 64 + lane];    // W3[k_t, 64+lane]
                const u64 g0 = rl_pair(gv0, t * 8 + row0);
                const u64 g1 = rl_pair(gv0, t * 8 + row1);
                if (t & 1) { accB[0] = pk_fma_s(g0, w3v, accB[0]);
                             accB[1] = pk_fma_s(g1, w3v, accB[1]); }
                else       { accA[0] = pk_fma_s(g0, w3v, accA[0]);
                             accA[1] = pk_fma_s(g1, w3v, accA[1]); }
            }
            if (h9) {
                f32x2 w3v;
                w3v[0] = w3s[8 * 128 + lane];
                w3v[1] = w3s[8 * 128 + 64 + lane];
                const u64 g0 = rl_pair(gv1, row0);
                const u64 g1 = rl_pair(gv1, row1);
                accB[0] = pk_fma_s(g0, w3v, accB[0]);
                accB[1] = pk_fma_s(g1, w3v, accB[1]);
            }
        }
        #pragma unroll
        for (int rr = 0; rr < 2; ++rr) {
            const f32x2 at = accA[rr] + accB[rr];
            const float am = at[0] + b3m;
            const float ap = at[1] + b3p;
            const float sp = fast_softplus(ap);
            const float zc = fmaf(sp, ep[rr], am);
            if (lane == i) { zk[rr] = zc; zt[2 * w + rr] = zc; }
        }
        // zt write ordered by next boundary's LGKM0+barrier

        bc = (bc < 2) ? bc + 1 : 0;
    }

    #pragma unroll
    for (int rr = 0; rr < 2; ++rr)
        out[(blk8 + 2 * w + rr) * DD + lane] = zk[rr];
}

extern "C" void kernel_launch(void* const* d_in, const int* in_sizes, int n_in,
                              void* d_out, int out_size, void* d_ws, size_t ws_size,
                              hipStream_t stream) {
    const float* ctx = (const float*)d_in[0];
    const float* eps = (const float*)d_in[1];
    const float* W1  = (const float*)d_in[2];
    const float* b1  = (const float*)d_in[3];
    const float* W2  = (const float*)d_in[4];
    const float* b2  = (const float*)d_in[5];
    const float* W3  = (const float*)d_in[6];
    const float* b3  = (const float*)d_in[7];
    (void)d_ws; (void)ws_size; (void)in_sizes; (void)n_in; (void)out_size;

    made_sample<<<BATCH / 8, 256, 0, stream>>>(ctx, eps, W1, b1, W2, b2, W3, b3,
                                               (float*)d_out);
}

// Round 9
// 207.484 us; speedup vs baseline: 1.2645x; 1.2645x over previous
//
#include <hip/hip_runtime.h>
#include <math.h>

#define DD 64
#define CC 128
#define HH 512
#define BATCH 4096

typedef __attribute__((ext_vector_type(2))) float f32x2;
typedef unsigned long long u64;
typedef unsigned short u16;

__device__ __forceinline__ f32x2 splat2(float x) { f32x2 v; v[0] = x; v[1] = x; return v; }

// packed FMA with the one legal scalar source: src0 is an SGPR pair {h,h}.
__device__ __forceinline__ f32x2 pk_fma_s(u64 hpair, f32x2 b, f32x2 c) {
    f32x2 d;
    asm("v_pk_fma_f32 %0, %1, %2, %3" : "=v"(d) : "s"(hpair), "v"(b), "v"(c));
    return d;
}

__device__ __forceinline__ float fast_softplus(float x) {
    float t = exp2f(-fabsf(x) * 1.44269504f);
    return fmaxf(x, 0.f) + 0.69314718f * log2f(1.f + t);
}

// wave-uniform broadcast via v_readlane (SGPR result)
__device__ __forceinline__ float bcast(float x, int l) {
    return __int_as_float(__builtin_amdgcn_readlane(__float_as_int(x), l));
}
// broadcast to an SGPR pair {x,x} for pk_fma_s (pair build is SALU, co-issues)
__device__ __forceinline__ u64 rl_pair(float x, int l) {
    unsigned u = (unsigned)__builtin_amdgcn_readlane(__float_as_int(x), l);
    return ((u64)u << 32) | u;
}

typedef const __attribute__((address_space(1))) void* as1_cptr;
typedef __attribute__((address_space(3))) void* as3_ptr;
__device__ __forceinline__ void glds16(const void* g, void* l) {
    __builtin_amdgcn_global_load_lds((as1_cptr)g, (as3_ptr)l, 16, 0, 0);
}

// ---- pre-kernel: W1,W2 fp32 -> bf16 (RNE) into workspace ----
// n = (DD+CC)*HH + HH*HH = 360448 elements, ~0.7 MB out. Runs once per launch.
__global__ void cvt_w(const float* __restrict__ W1, const float* __restrict__ W2,
                      u16* __restrict__ o) {
    const int n1 = (DD + CC) * HH;
    const int n  = n1 + HH * HH;
    for (int i = blockIdx.x * blockDim.x + threadIdx.x; i < n;
         i += gridDim.x * blockDim.x) {
        const float x = (i < n1) ? W1[i] : W2[i - n1];
        const unsigned u = __float_as_uint(x);
        o[i] = (u16)((u + 0x7fffu + ((u >> 16) & 1u)) >> 16);   // RNE
    }
}

// R9 = R4 structure (best-known: 8 waves x R=1, grid 512, 2 blocks/CU, plain
// double-buffer + __syncthreads) with BF16-STAGED W1/W2.
//
// Why: elimination record R1-R8 (VALU count / ILP / TLP / drain / barriers)
// leaves LDS READ VOLUME as R4's binder — per wave per iter ~18 b128 (W2)
// + 9 ds_read2 (W3) + 2 b128 (W1) ~ 205cy LDS-pipe; x16 waves/CU ~ 3300cy
// of the 3840cy window (saturated). bf16 weights halve W2/W1 read bytes:
// one ds_read_b128 per row per lane (8 bf16 = the lane's 8 owned columns),
// unpacked to fp32 with 2 VALU/dword (shift/and, exact). W3, biases, and all
// activations/accumulators remain fp32. Staging: one glds16 per 512-col row.
__global__ __launch_bounds__(512, 4) void made_sample(
    const float* __restrict__ ctx,   // (B, C)
    const float* __restrict__ eps,   // (B, D)
    const u16*   __restrict__ w1b,   // (D+C, H) bf16
    const float* __restrict__ b1,    // (H)
    const u16*   __restrict__ w2b,   // (H, H) bf16
    const float* __restrict__ b2,    // (H)
    const float* __restrict__ W3,    // (H, 2D) fp32
    const float* __restrict__ b3,    // (2D)
    float* __restrict__ out)         // (B, D)
{
    const int lane  = threadIdx.x & 63;
    const int w     = threadIdx.x >> 6;          // wave 0..7
    const int rrow  = blockIdx.x * 8 + w;        // 1 batch row per wave
    const int jbase = 8 * lane;

    __shared__ u16   sbuf[2][10 * HH];           // 2 x 10 KB (9 W2 + 1 W1 rows, bf16)
    __shared__ float w3sb[2][5 * 256];           // 2 x 5 KB  (5 W3 pair slots, fp32)

    int deg[8];
    #pragma unroll
    for (int u = 0; u < 8; ++u) deg[u] = (jbase + u) % 63 + 1;

    // one b128 -> lane's 8 owned bf16 columns -> 4 f32x2 (exact unpack)
    auto load8bf = [&](const u16* base_, f32x2* w_) {
        const uint4 v = *(const uint4*)(base_ + lane * 8);
        w_[0][0] = __uint_as_float(v.x << 16);
        w_[0][1] = __uint_as_float(v.x & 0xFFFF0000u);
        w_[1][0] = __uint_as_float(v.y << 16);
        w_[1][1] = __uint_as_float(v.y & 0xFFFF0000u);
        w_[2][0] = __uint_as_float(v.z << 16);
        w_[2][1] = __uint_as_float(v.z & 0xFFFF0000u);
        w_[3][0] = __uint_as_float(v.w << 16);
        w_[3][1] = __uint_as_float(v.w & 0xFFFF0000u);
    };
    // stage one 512-col bf16 row (1 KB) with a single glds16
    auto stage_row = [&](const u16* src, u16* dst) {
        glds16(src + lane * 8, dst);
    };
    // W3 rows k0,k1 (128 floats each, fp32) into one 1KB pair slot:
    // lanes 0..31 carry row k0, lanes 32..63 row k1.
    auto stage_w3pair = [&](int k0, int k1, float* dst) {
        const float* g = (lane < 32) ? (W3 + k0 * (2 * DD) + lane * 4)
                                     : (W3 + k1 * (2 * DD) + (lane - 32) * 4);
        glds16(g, dst);
    };

    f32x2 p1[4], p2[4], acc;
    #pragma unroll
    for (int j = 0; j < 4; ++j) {
        p1[j][0] = b1[jbase + 2 * j]; p1[j][1] = b1[jbase + 2 * j + 1];
        p2[j][0] = b2[jbase + 2 * j]; p2[j][1] = b2[jbase + 2 * j + 1];
    }
    acc = splat2(0.f);

    const float ca = ctx[rrow * CC + lane];
    const float cb = ctx[rrow * CC + 64 + lane];
    const float ep = eps[rrow * DD + lane];
    const float b3m = b3[lane];        // bias for mean col `lane`
    const float b3p = b3[64 + lane];   // bias for prescale col `lane`

    // ctx chunk ch: W1 rows DD+8ch..DD+8ch+7 -> slots 0..7 (1 row per wave)
    auto stage_ctx = [&](int ch, u16* buf) {
        stage_row(w1b + (DD + 8 * ch + w) * HH, buf + w * HH);
    };
    // staging for main step `in`, spread over 8 waves (R4 scheme):
    //   wave w (0..7): W2 row basen+63*w -> slot w
    //   wave 0: + W2 row basen+504 -> slot 8      (iff basen<8)
    //   wave 1: + W1 row `in` -> slot 9
    //   waves 2..5: W3 pair p=w-2 (rows basen+63*2p, basen+63*(2p+1))
    //   wave 6: W3 pair 4 (row basen+504 dup)     (iff basen<8)
    auto stage_step = [&](int in, u16* buf, float* w3buf) {
        if (in == 0) {                       // step 0 needs only W1 row 0
            if (w == 1) stage_row(w1b, buf + 9 * HH);
            return;
        }
        const int basen = in - 1;
        const bool h9n = basen < 8;
        stage_row(w2b + (basen + 63 * w) * HH, buf + w * HH);
        if (w == 0 && h9n) stage_row(w2b + (basen + 504) * HH, buf + 8 * HH);
        if (w == 1) stage_row(w1b + in * HH, buf + 9 * HH);
        if (w >= 2 && w <= 5) {
            const int p = w - 2;
            stage_w3pair(basen + 63 * (2 * p), basen + 63 * (2 * p + 1),
                         w3buf + p * 256);
        }
        if (w == 6 && h9n)
            stage_w3pair(basen + 504, basen + 504, w3buf + 4 * 256);
    };

    // ---- context init: pre1 += ctx @ W1[D:,:], 16 chunks of 8 rows ----
    stage_ctx(0, sbuf[0]);
    __syncthreads();
    #pragma unroll 1
    for (int ch = 0; ch < 16; ++ch) {
        u16* cur = sbuf[ch & 1];
        if (ch < 15) stage_ctx(ch + 1, sbuf[(ch + 1) & 1]);
        else         stage_step(0, sbuf[0], w3sb[0]);   // (16)&1==0: parity OK
        #pragma unroll
        for (int q = 0; q < 8; ++q) {
            f32x2 cw[4];
            load8bf(cur + q * HH, cw);
            const int c = 8 * ch + q;
            const u64 cvp = rl_pair((ch < 8) ? ca : cb, c & 63);
            #pragma unroll
            for (int j = 0; j < 4; ++j) p1[j] = pk_fma_s(cvp, cw[j], p1[j]);
        }
        __syncthreads();
    }

    float z = 0.f;

    // ---- autoregressive main loop (R4 schedule, unchanged) ----
    #pragma unroll 1
    for (int i = 0; i < DD; ++i) {
        u16* cur = sbuf[i & 1];
        const float* w3s = w3sb[i & 1];

        // issue next-step staging first (vmcnt countdown starts earliest)
        if (i < 63) stage_step(i + 1, sbuf[(i + 1) & 1], w3sb[(i + 1) & 1]);

        f32x2 w1v[4];
        load8bf(cur + 9 * HH, w1v);

        if (i > 0) {                      // i==0: no unit has deg==0, all h==0
            const int base = i - 1;
            const bool h9 = base < 8;     // 9th finalizing unit exists (i<=8)

            // (a) select finalized h1 (deg==i)
            float m0 = 0.f;
            #pragma unroll
            for (int u = 0; u < 8; ++u)
                m0 = (deg[u] == i) ? p1[u >> 1][u & 1] : m0;
            m0 = fmaxf(m0, 0.f);

            // (b) rank update of pre2 (packed FMA, SGPR-pair h operand)
            #pragma unroll
            for (int t = 0; t < 8; ++t) {
                const int k = base + 63 * t;
                f32x2 wv[4];
                load8bf(cur + t * HH, wv);
                const u64 h0 = rl_pair(m0, k >> 3);
                #pragma unroll
                for (int j = 0; j < 4; ++j) p2[j] = pk_fma_s(h0, wv[j], p2[j]);
            }
            if (h9) {                     // t=8: unit base+504, owner lane 63
                f32x2 wv[4];
                load8bf(cur + 8 * HH, wv);
                const u64 h0 = rl_pair(m0, 63);
                #pragma unroll
                for (int j = 0; j < 4; ++j) p2[j] = pk_fma_s(h0, wv[j], p2[j]);
            }

            // (c) capture newly-final h2 (deg==i)
            float g0 = 0.f;
            #pragma unroll
            for (int u = 0; u < 8; ++u)
                g0 = (deg[u] == i) ? p2[u >> 1][u & 1] : g0;
            g0 = fmaxf(g0, 0.f);

            // (d) incremental W3 accumulation (fp32 staged pairs)
            #pragma unroll
            for (int t = 0; t < 8; ++t) {
                const int k = base + 63 * t;
                const float wa = w3s[t * 128 + lane];        // W3[k, lane]
                const float wb = w3s[t * 128 + 64 + lane];   // W3[k, 64+lane]
                const float h0 = bcast(g0, k >> 3);
                acc[0] = fmaf(h0, wa, acc[0]);
                acc[1] = fmaf(h0, wb, acc[1]);
            }
            if (h9) {
                const float wa = w3s[8 * 128 + lane];
                const float wb = w3s[8 * 128 + 64 + lane];
                const float h0 = bcast(g0, 63);
                acc[0] = fmaf(h0, wa, acc[0]);
                acc[1] = fmaf(h0, wb, acc[1]);
            }
        }

        // (e) z_i: column i's totals live in lane i; every lane computes its
        // own candidate (parallel), one readlane extracts; feed back into p1.
        {
            const float am = acc[0] + b3m;
            const float ap = acc[1] + b3p;
            const float sp = fast_softplus(ap);
            const float zc = fmaf(sp, ep, am);
            if (lane == i) z = bcast(zc, i);
            const u64 zp = rl_pair(zc, i);
            #pragma unroll
            for (int j = 0; j < 4; ++j) p1[j] = pk_fma_s(zp, w1v[j], p1[j]);
        }

        __syncthreads();
    }

    out[rrow * DD + lane] = z;
}

extern "C" void kernel_launch(void* const* d_in, const int* in_sizes, int n_in,
                              void* d_out, int out_size, void* d_ws, size_t ws_size,
                              hipStream_t stream) {
    const float* ctx = (const float*)d_in[0];
    const float* eps = (const float*)d_in[1];
    const float* W1  = (const float*)d_in[2];
    const float* b1  = (const float*)d_in[3];
    const float* W2  = (const float*)d_in[4];
    const float* b2  = (const float*)d_in[5];
    const float* W3  = (const float*)d_in[6];
    const float* b3  = (const float*)d_in[7];
    (void)d_ws; (void)ws_size; (void)in_sizes; (void)n_in; (void)out_size;

    u16* wsb = (u16*)d_ws;                        // 0.72 MB used
    cvt_w<<<704, 512, 0, stream>>>(W1, W2, wsb);
    made_sample<<<BATCH / 8, 512, 0, stream>>>(ctx, eps,
                                               wsb, b1,
                                               wsb + (DD + CC) * HH, b2,
                                               W3, b3, (float*)d_out);
}

// Round 10
// 194.366 us; speedup vs baseline: 1.3498x; 1.0675x over previous
//
#include <hip/hip_runtime.h>
#include <hip/hip_fp16.h>
#include <math.h>

#define DD 64
#define CC 128
#define HH 512
#define BATCH 4096

typedef __attribute__((ext_vector_type(2))) float f32x2;
typedef unsigned long long u64;
typedef unsigned short u16;

__device__ __forceinline__ float fast_softplus(float x) {
    float t = exp2f(-fabsf(x) * 1.44269504f);
    return fmaxf(x, 0.f) + 0.69314718f * log2f(1.f + t);
}

// wave-uniform broadcast via v_readlane (SGPR result)
__device__ __forceinline__ float bcast(float x, int l) {
    return __int_as_float(__builtin_amdgcn_readlane(__float_as_int(x), l));
}

// hardware mixed-precision FMA: acc(f32) += f16(half of wpair) * h(f32 SGPR).
// The f16->f32 conversion happens INSIDE the FMA (VOP3P v_fma_mix_f32):
// zero unpack instructions, zero extra chain latency (R9's failure mode).
__device__ __forceinline__ void fmix_lo(float& acc, unsigned wpair, float h) {
    asm("v_fma_mix_f32 %0, %1, %2, %0 op_sel_hi:[1,0,0]"
        : "+v"(acc) : "v"(wpair), "s"(h));
}
__device__ __forceinline__ void fmix_hi(float& acc, unsigned wpair, float h) {
    asm("v_fma_mix_f32 %0, %1, %2, %0 op_sel:[1,0,0] op_sel_hi:[1,0,0]"
        : "+v"(acc) : "v"(wpair), "s"(h));
}
// apply 8 columns (one uint4 of 8 f16 weights) into acc[0..7]
__device__ __forceinline__ void fmix8(float* a, uint4 v, float h) {
    fmix_lo(a[0], v.x, h); fmix_hi(a[1], v.x, h);
    fmix_lo(a[2], v.y, h); fmix_hi(a[3], v.y, h);
    fmix_lo(a[4], v.z, h); fmix_hi(a[5], v.z, h);
    fmix_lo(a[6], v.w, h); fmix_hi(a[7], v.w, h);
}

typedef const __attribute__((address_space(1))) void* as1_cptr;
typedef __attribute__((address_space(3))) void* as3_ptr;
__device__ __forceinline__ void glds16(const void* g, void* l) {
    __builtin_amdgcn_global_load_lds((as1_cptr)g, (as3_ptr)l, 16, 0, 0);
}

// ---- pre-kernel: W1,W2 fp32 -> f16 (RNE) into workspace ----
__global__ void cvt_w(const float* __restrict__ W1, const float* __restrict__ W2,
                      u16* __restrict__ o) {
    const int n1 = (DD + CC) * HH;
    const int n  = n1 + HH * HH;
    for (int i = blockIdx.x * blockDim.x + threadIdx.x; i < n;
         i += gridDim.x * blockDim.x) {
        const float x = (i < n1) ? W1[i] : W2[i - n1];
        const __half h = __float2half(x);          // RNE
        o[i] = *(const u16*)&h;
    }
}

// R10 = R4 structure (best: 8 waves x R=1, grid 512, 2 blocks/CU, plain
// double-buffer) with F16-staged W1/W2 consumed via v_fma_mix_f32.
//
// Model (calibrated R2/R4/R9): R4 is LDS-read-pipe SATURATED (16 waves x
// 20 b128 x ~12cy = 3840cy = the whole iteration window). R9's bf16 halved
// LDS bytes but paid 8 VALU unpack per b128 ON the ds_read->FMA chain ->
// VALU time +48%, dur +23%. fma_mix does the f16->f32 conversion inside the
// FMA: LDS 3840->~2780cy (1 b128/row), VALU +36 instr/wave/iter only, and
// the dependency shape (ds_read -> FMA) is identical to R4-f32.
// W3/biases/activations/accumulators all stay fp32.
__global__ __launch_bounds__(512, 4) void made_sample(
    const float* __restrict__ ctx,   // (B, C)
    const float* __restrict__ eps,   // (B, D)
    const u16*   __restrict__ w1h,   // (D+C, H) f16
    const float* __restrict__ b1,    // (H)
    const u16*   __restrict__ w2h,   // (H, H) f16
    const float* __restrict__ b2,    // (H)
    const float* __restrict__ W3,    // (H, 2D) fp32
    const float* __restrict__ b3,    // (2D)
    float* __restrict__ out)         // (B, D)
{
    const int lane  = threadIdx.x & 63;
    const int w     = threadIdx.x >> 6;          // wave 0..7
    const int rrow  = blockIdx.x * 8 + w;        // 1 batch row per wave
    const int jbase = 8 * lane;

    __shared__ u16   sbuf[2][10 * HH];           // 2 x 10 KB (9 W2 + 1 W1 rows, f16)
    __shared__ float w3sb[2][5 * 256];           // 2 x 5 KB  (5 W3 pair slots, fp32)

    int deg[8];
    #pragma unroll
    for (int u = 0; u < 8; ++u) deg[u] = (jbase + u) % 63 + 1;

    // stage one 512-col f16 row (1 KB) with a single glds16
    auto stage_row = [&](const u16* src, u16* dst) {
        glds16(src + lane * 8, dst);
    };
    // W3 rows k0,k1 (128 floats each, fp32) into one 1KB pair slot:
    // lanes 0..31 carry row k0, lanes 32..63 row k1.
    auto stage_w3pair = [&](int k0, int k1, float* dst) {
        const float* g = (lane < 32) ? (W3 + k0 * (2 * DD) + lane * 4)
                                     : (W3 + k1 * (2 * DD) + (lane - 32) * 4);
        glds16(g, dst);
    };

    // per-lane state: 8 owned units, scalar f32 accumulators
    float p1[8], p2[8];
    #pragma unroll
    for (int u = 0; u < 8; ++u) { p1[u] = b1[jbase + u]; p2[u] = b2[jbase + u]; }
    float accm = 0.f, accp = 0.f;

    const float ca = ctx[rrow * CC + lane];
    const float cb = ctx[rrow * CC + 64 + lane];
    const float ep = eps[rrow * DD + lane];
    const float b3m = b3[lane];        // bias for mean col `lane`
    const float b3p = b3[64 + lane];   // bias for prescale col `lane`

    // ctx chunk ch: W1 rows DD+8ch..DD+8ch+7 -> slots 0..7 (1 row per wave)
    auto stage_ctx = [&](int ch, u16* buf) {
        stage_row(w1h + (DD + 8 * ch + w) * HH, buf + w * HH);
    };
    // staging for main step `in`, spread over 8 waves (R4 scheme):
    auto stage_step = [&](int in, u16* buf, float* w3buf) {
        if (in == 0) {                       // step 0 needs only W1 row 0
            if (w == 1) stage_row(w1h, buf + 9 * HH);
            return;
        }
        const int basen = in - 1;
        const bool h9n = basen < 8;
        stage_row(w2h + (basen + 63 * w) * HH, buf + w * HH);
        if (w == 0 && h9n) stage_row(w2h + (basen + 504) * HH, buf + 8 * HH);
        if (w == 1) stage_row(w1h + in * HH, buf + 9 * HH);
        if (w >= 2 && w <= 5) {
            const int p = w - 2;
            stage_w3pair(basen + 63 * (2 * p), basen + 63 * (2 * p + 1),
                         w3buf + p * 256);
        }
        if (w == 6 && h9n)
            stage_w3pair(basen + 504, basen + 504, w3buf + 4 * 256);
    };

    // ---- context init: pre1 += ctx @ W1[D:,:], 16 chunks of 8 rows ----
    stage_ctx(0, sbuf[0]);
    __syncthreads();
    #pragma unroll 1
    for (int ch = 0; ch < 16; ++ch) {
        u16* cur = sbuf[ch & 1];
        if (ch < 15) stage_ctx(ch + 1, sbuf[(ch + 1) & 1]);
        else         stage_step(0, sbuf[0], w3sb[0]);   // (16)&1==0: parity OK
        #pragma unroll
        for (int q = 0; q < 8; ++q) {
            const uint4 wv = *(const uint4*)(cur + q * HH + lane * 8);
            const int c = 8 * ch + q;
            const float cv = bcast((ch < 8) ? ca : cb, c & 63);
            fmix8(p1, wv, cv);
        }
        __syncthreads();
    }

    float z = 0.f;

    // ---- autoregressive main loop (R4 schedule, unchanged) ----
    #pragma unroll 1
    for (int i = 0; i < DD; ++i) {
        u16* cur = sbuf[i & 1];
        const float* w3s = w3sb[i & 1];

        // issue next-step staging first (vmcnt countdown starts earliest)
        if (i < 63) stage_step(i + 1, sbuf[(i + 1) & 1], w3sb[(i + 1) & 1]);

        const uint4 w1v = *(const uint4*)(cur + 9 * HH + lane * 8);

        if (i > 0) {                      // i==0: no unit has deg==0, all h==0
            const int base = i - 1;
            const bool h9 = base < 8;     // 9th finalizing unit exists (i<=8)

            // (a) select finalized h1 (deg==i)
            float m0 = 0.f;
            #pragma unroll
            for (int u = 0; u < 8; ++u)
                m0 = (deg[u] == i) ? p1[u] : m0;
            m0 = fmaxf(m0, 0.f);

            // (b) rank update of pre2: one b128 + 8 fma_mix per row
            #pragma unroll
            for (int t = 0; t < 8; ++t) {
                const int k = base + 63 * t;
                const uint4 wv = *(const uint4*)(cur + t * HH + lane * 8);
                const float h0 = bcast(m0, k >> 3);
                fmix8(p2, wv, h0);
            }
            if (h9) {                     // t=8: unit base+504, owner lane 63
                const uint4 wv = *(const uint4*)(cur + 8 * HH + lane * 8);
                const float h0 = bcast(m0, 63);
                fmix8(p2, wv, h0);
            }

            // (c) capture newly-final h2 (deg==i)
            float g0 = 0.f;
            #pragma unroll
            for (int u = 0; u < 8; ++u)
                g0 = (deg[u] == i) ? p2[u] : g0;
            g0 = fmaxf(g0, 0.f);

            // (d) incremental W3 accumulation (fp32 staged pairs)
            #pragma unroll
            for (int t = 0; t < 8; ++t) {
                const int k = base + 63 * t;
                const float wa = w3s[t * 128 + lane];        // W3[k, lane]
                const float wb = w3s[t * 128 + 64 + lane];   // W3[k, 64+lane]
                const float h0 = bcast(g0, k >> 3);
                accm = fmaf(h0, wa, accm);
                accp = fmaf(h0, wb, accp);
            }
            if (h9) {
                const float wa = w3s[8 * 128 + lane];
                const float wb = w3s[8 * 128 + 64 + lane];
                const float h0 = bcast(g0, 63);
                accm = fmaf(h0, wa, accm);
                accp = fmaf(h0, wb, accp);
            }
        }

        // (e) z_i: column i's totals live in lane i; every lane computes its
        // own candidate (parallel), one readlane extracts; feed back into p1.
        {
            const float am = accm + b3m;
            const float ap = accp + b3p;
            const float sp = fast_softplus(ap);
            const float zc = fmaf(sp, ep, am);
            const float zi = bcast(zc, i);
            if (lane == i) z = zi;
            fmix8(p1, w1v, zi);
        }

        __syncthreads();
    }

    out[rrow * DD + lane] = z;
}

extern "C" void kernel_launch(void* const* d_in, const int* in_sizes, int n_in,
                              void* d_out, int out_size, void* d_ws, size_t ws_size,
                              hipStream_t stream) {
    const float* ctx = (const float*)d_in[0];
    const float* eps = (const float*)d_in[1];
    const float* W1  = (const float*)d_in[2];
    const float* b1  = (const float*)d_in[3];
    const float* W2  = (const float*)d_in[4];
    const float* b2  = (const float*)d_in[5];
    const float* W3  = (const float*)d_in[6];
    const float* b3  = (const float*)d_in[7];
    (void)d_ws; (void)ws_size; (void)in_sizes; (void)n_in; (void)out_size;

    u16* wsh = (u16*)d_ws;                        // 0.72 MB used
    cvt_w<<<704, 512, 0, stream>>>(W1, W2, wsh);
    made_sample<<<BATCH / 8, 512, 0, stream>>>(ctx, eps,
                                               wsh, b1,
                                               wsh + (DD + CC) * HH, b2,
                                               W3, b3, (float*)d_out);
}

// Round 11
// 188.986 us; speedup vs baseline: 1.3883x; 1.0285x over previous
//
#include <hip/hip_runtime.h>
#include <math.h>

#define DD 64
#define CC 128
#define HH 512
#define BATCH 4096

typedef __attribute__((ext_vector_type(2))) float f32x2;
typedef unsigned long long u64;

__device__ __forceinline__ f32x2 splat2(float x) { f32x2 v; v[0] = x; v[1] = x; return v; }

// packed FMA with the one legal scalar source: src0 is an SGPR pair {h,h}.
__device__ __forceinline__ f32x2 pk_fma_s(u64 hpair, f32x2 b, f32x2 c) {
    f32x2 d;
    asm("v_pk_fma_f32 %0, %1, %2, %3" : "=v"(d) : "s"(hpair), "v"(b), "v"(c));
    return d;
}

__device__ __forceinline__ float fast_softplus(float x) {
    float t = exp2f(-fabsf(x) * 1.44269504f);
    return fmaxf(x, 0.f) + 0.69314718f * log2f(1.f + t);
}

// wave-uniform broadcast via v_readlane (SGPR result)
__device__ __forceinline__ float bcast(float x, int l) {
    return __int_as_float(__builtin_amdgcn_readlane(__float_as_int(x), l));
}
// broadcast to an SGPR pair {x,x} for pk_fma_s (pair build is SALU, co-issues)
__device__ __forceinline__ u64 rl_pair(float x, int l) {
    unsigned u = (unsigned)__builtin_amdgcn_readlane(__float_as_int(x), l);
    return ((u64)u << 32) | u;
}

typedef const __attribute__((address_space(1))) void* as1_cptr;
typedef __attribute__((address_space(3))) void* as3_ptr;
__device__ __forceinline__ void glds16(const float* g, float* l) {
    __builtin_amdgcn_global_load_lds((as1_cptr)g, (as3_ptr)l, 16, 0, 0);
}

// R11 = R4 (best measured: 127.3us; 8 waves x R=1, grid 512, 2 blocks/CU,
// plain double-buffer + __syncthreads, f32 W2 via pk_fma_s) with the W3 and
// W1-feedback reads moved OFF the LDS pipe:
//   - W3 rows (9 x 2 floats/lane/iter) and the W1 feedback row (8 floats/lane)
//     are prefetched at iteration top DIRECTLY from global (L2-resident:
//     W3 = 256KB total, same rows read by all 512 blocks; W1 row = 2KB/step).
//     Addresses depend only on i; values consumed ~1000+cy later -> latency
//     hidden; ZERO added chain ops (R9/R10's failure mode was paying VALU
//     per LDS byte saved; this slice has no exchange rate).
//   - LDS now stages only W2 (9 slots f32): 36KB vs 50KB, and per-wave LDS
//     reads drop 20 b128 + 9 ds_read2 -> 18 b128 (-27% LDS-pipe time at
//     16 waves/CU, where R4's window was ~LDS-saturated).
//   - W2 stays f32 (packed FMA needs f32; f16/bf16 variants regressed).
__global__ __launch_bounds__(512, 4) void made_sample(
    const float* __restrict__ ctx,   // (B, C)
    const float* __restrict__ eps,   // (B, D)
    const float* __restrict__ W1,    // (D+C, H)
    const float* __restrict__ b1,    // (H)
    const float* __restrict__ W2,    // (H, H)
    const float* __restrict__ b2,    // (H)
    const float* __restrict__ W3,    // (H, 2D)
    const float* __restrict__ b3,    // (2D)
    float* __restrict__ out)         // (B, D)
{
    const int lane  = threadIdx.x & 63;
    const int w     = threadIdx.x >> 6;          // wave 0..7
    const int rrow  = blockIdx.x * 8 + w;        // 1 batch row per wave
    const int jbase = 8 * lane;

    __shared__ float sbuf[2][9 * HH];            // 2 x 18 KB (9 W2 row slots)

    int deg[8];
    #pragma unroll
    for (int u = 0; u < 8; ++u) deg[u] = (jbase + u) % 63 + 1;

    // split-half LDS read: slot base -> 4 f32x2 (8 floats) for this lane
    auto load8v = [&](const float* base_, f32x2* r_) {
        float4 a = *(const float4*)(base_ + lane * 4);
        float4 b = *(const float4*)(base_ + 256 + lane * 4);
        r_[0][0] = a.x; r_[0][1] = a.y; r_[1][0] = a.z; r_[1][1] = a.w;
        r_[2][0] = b.x; r_[2][1] = b.y; r_[3][0] = b.z; r_[3][1] = b.w;
    };
    auto stage_row = [&](const float* src, float* dst) {
        glds16(src + lane * 8,     dst);
        glds16(src + lane * 8 + 4, dst + 256);
    };

    f32x2 p1[4], p2[4], acc;
    #pragma unroll
    for (int j = 0; j < 4; ++j) {
        p1[j][0] = b1[jbase + 2 * j]; p1[j][1] = b1[jbase + 2 * j + 1];
        p2[j][0] = b2[jbase + 2 * j]; p2[j][1] = b2[jbase + 2 * j + 1];
    }
    acc = splat2(0.f);

    const float ca = ctx[rrow * CC + lane];
    const float cb = ctx[rrow * CC + 64 + lane];
    const float ep = eps[rrow * DD + lane];
    const float b3m = b3[lane];        // bias for mean col `lane`
    const float b3p = b3[64 + lane];   // bias for prescale col `lane`

    // ctx chunk ch: W1 rows DD+8ch..DD+8ch+7 -> slots 0..7 (1 row per wave)
    auto stage_ctx = [&](int ch, float* buf) {
        stage_row(W1 + (DD + 8 * ch + w) * HH, buf + w * HH);
    };
    // staging for main step `in`: W2 rows ONLY (W3/W1 now global-direct).
    //   wave w (0..7): W2 row basen+63*w -> slot w
    //   wave 0: + W2 row basen+504 -> slot 8      (iff basen<8)
    auto stage_step = [&](int in, float* buf) {
        if (in == 0) return;                 // step 0 reads no W2
        const int basen = in - 1;
        stage_row(W2 + (basen + 63 * w) * HH, buf + w * HH);
        if (w == 0 && basen < 8) stage_row(W2 + (basen + 504) * HH, buf + 8 * HH);
    };

    // ---- context init: pre1 += ctx @ W1[D:,:], 16 chunks of 8 rows ----
    stage_ctx(0, sbuf[0]);
    __syncthreads();
    #pragma unroll 1
    for (int ch = 0; ch < 16; ++ch) {
        float* cur = sbuf[ch & 1];
        if (ch < 15) stage_ctx(ch + 1, sbuf[(ch + 1) & 1]);
        #pragma unroll
        for (int q = 0; q < 8; ++q) {
            f32x2 cw[4];
            load8v(cur + q * HH, cw);
            const int c = 8 * ch + q;
            const u64 cvp = rl_pair((ch < 8) ? ca : cb, c & 63);
            #pragma unroll
            for (int j = 0; j < 4; ++j) p1[j] = pk_fma_s(cvp, cw[j], p1[j]);
        }
        __syncthreads();
    }

    float z = 0.f;

    // ---- autoregressive main loop (R4 schedule; W3/W1 global-prefetched) ----
    #pragma unroll 1
    for (int i = 0; i < DD; ++i) {
        float* cur = sbuf[i & 1];

        // issue next-step W2 staging first (vmcnt countdown starts earliest)
        if (i < 63) stage_step(i + 1, sbuf[(i + 1) & 1]);

        // global prefetches for THIS iteration (L2-hot; consumed in (d)/(e))
        const float4 w1a = *(const float4*)(W1 + i * HH + jbase);
        const float4 w1b4 = *(const float4*)(W1 + i * HH + jbase + 4);
        float w3a[9], w3b[9];
        if (i > 0) {
            const int base = i - 1;
            #pragma unroll
            for (int t = 0; t < 9; ++t) {
                int k = base + 63 * t;
                if (k >= HH) k = HH - 1;             // t=8 clamp; use guarded
                w3a[t] = W3[k * (2 * DD) + lane];        // W3[k, lane]
                w3b[t] = W3[k * (2 * DD) + 64 + lane];   // W3[k, 64+lane]
            }
        }

        if (i > 0) {                      // i==0: no unit has deg==0, all h==0
            const int base = i - 1;
            const bool h9 = base < 8;     // 9th finalizing unit exists (i<=8)

            // (a) select finalized h1 (deg==i)
            float m0 = 0.f;
            #pragma unroll
            for (int u = 0; u < 8; ++u)
                m0 = (deg[u] == i) ? p1[u >> 1][u & 1] : m0;
            m0 = fmaxf(m0, 0.f);

            // (b) rank update of pre2 (packed FMA, SGPR-pair h operand)
            #pragma unroll
            for (int t = 0; t < 8; ++t) {
                const int k = base + 63 * t;
                f32x2 wv[4];
                load8v(cur + t * HH, wv);
                const u64 h0 = rl_pair(m0, k >> 3);
                #pragma unroll
                for (int j = 0; j < 4; ++j) p2[j] = pk_fma_s(h0, wv[j], p2[j]);
            }
            if (h9) {                     // t=8: unit base+504, owner lane 63
                f32x2 wv[4];
                load8v(cur + 8 * HH, wv);
                const u64 h0 = rl_pair(m0, 63);
                #pragma unroll
                for (int j = 0; j < 4; ++j) p2[j] = pk_fma_s(h0, wv[j], p2[j]);
            }

            // (c) capture newly-final h2 (deg==i)
            float g0 = 0.f;
            #pragma unroll
            for (int u = 0; u < 8; ++u)
                g0 = (deg[u] == i) ? p2[u >> 1][u & 1] : g0;
            g0 = fmaxf(g0, 0.f);

            // (d) incremental W3 accumulation from prefetched registers
            #pragma unroll
            for (int t = 0; t < 8; ++t) {
                const int k = base + 63 * t;
                const float h0 = bcast(g0, k >> 3);
                acc[0] = fmaf(h0, w3a[t], acc[0]);
                acc[1] = fmaf(h0, w3b[t], acc[1]);
            }
            if (h9) {
                const float h0 = bcast(g0, 63);
                acc[0] = fmaf(h0, w3a[8], acc[0]);
                acc[1] = fmaf(h0, w3b[8], acc[1]);
            }
        }

        // (e) z_i: column i's totals live in lane i; every lane computes its
        // own candidate (parallel), one readlane extracts; feed back into p1.
        {
            f32x2 w1v[4];
            w1v[0][0] = w1a.x;  w1v[0][1] = w1a.y;
            w1v[1][0] = w1a.z;  w1v[1][1] = w1a.w;
            w1v[2][0] = w1b4.x; w1v[2][1] = w1b4.y;
            w1v[3][0] = w1b4.z; w1v[3][1] = w1b4.w;
            const float am = acc[0] + b3m;
            const float ap = acc[1] + b3p;
            const float sp = fast_softplus(ap);
            const float zc = fmaf(sp, ep, am);
            if (lane == i) z = bcast(zc, i);
            const u64 zp = rl_pair(zc, i);
            #pragma unroll
            for (int j = 0; j < 4; ++j) p1[j] = pk_fma_s(zp, w1v[j], p1[j]);
        }

        __syncthreads();
    }

    out[rrow * DD + lane] = z;
}

extern "C" void kernel_launch(void* const* d_in, const int* in_sizes, int n_in,
                              void* d_out, int out_size, void* d_ws, size_t ws_size,
                              hipStream_t stream) {
    const float* ctx = (const float*)d_in[0];
    const float* eps = (const float*)d_in[1];
    const float* W1  = (const float*)d_in[2];
    const float* b1  = (const float*)d_in[3];
    const float* W2  = (const float*)d_in[4];
    const float* b2  = (const float*)d_in[5];
    const float* W3  = (const float*)d_in[6];
    const float* b3  = (const float*)d_in[7];
    (void)d_ws; (void)ws_size; (void)in_sizes; (void)n_in; (void)out_size;

    made_sample<<<BATCH / 8, 512, 0, stream>>>(ctx, eps, W1, b1, W2, b2, W3, b3,
                                               (float*)d_out);
}

// Round 12
// 174.500 us; speedup vs baseline: 1.5035x; 1.0830x over previous
//
#include <hip/hip_runtime.h>
#include <math.h>

#define DD 64
#define CC 128
#define HH 512
#define BATCH 4096

typedef __attribute__((ext_vector_type(2))) float f32x2;
typedef unsigned long long u64;

__device__ __forceinline__ f32x2 splat2(float x) { f32x2 v; v[0] = x; v[1] = x; return v; }

// packed FMA with the one legal scalar source: src0 is an SGPR pair {h,h}.
// Saves the 2 v_mov splat per broadcast scalar (marshaling moves to SALU).
__device__ __forceinline__ f32x2 pk_fma_s(u64 hpair, f32x2 b, f32x2 c) {
    f32x2 d;
    asm("v_pk_fma_f32 %0, %1, %2, %3" : "=v"(d) : "s"(hpair), "v"(b), "v"(c));
    return d;
}

__device__ __forceinline__ float fast_softplus(float x) {
    float t = exp2f(-fabsf(x) * 1.44269504f);
    return fmaxf(x, 0.f) + 0.69314718f * log2f(1.f + t);
}

// wave-uniform broadcast via v_readlane (SGPR result)
__device__ __forceinline__ float bcast(float x, int l) {
    return __int_as_float(__builtin_amdgcn_readlane(__float_as_int(x), l));
}
// broadcast to an SGPR pair {x,x} for pk_fma_s (build is SALU, co-issues)
__device__ __forceinline__ u64 rl_pair(float x, int l) {
    unsigned u = (unsigned)__builtin_amdgcn_readlane(__float_as_int(x), l);
    return ((u64)u << 32) | u;
}

typedef const __attribute__((address_space(1))) void* as1_cptr;
typedef __attribute__((address_space(3))) void* as3_ptr;
__device__ __forceinline__ void glds16(const float* g, float* l) {
    __builtin_amdgcn_global_load_lds((as1_cptr)g, (as3_ptr)l, 16, 0, 0);
}

// FINAL (session best, R4): one block = 8 waves x R=1 row = 8 batch rows;
// grid 512 -> 2 blocks/CU, 16 waves/CU = 4 waves/SIMD.
//
// Session elimination record (R1-R11, each with falsifiable prediction):
//   - VALU instruction count (R1: pk_fma halved FMA stream -> -3.5% only)
//   - ILP / load hoisting (R2 sunk by compiler; R5 pinned cluster REGRESSED:
//     compiler's natural ds_read<->FMA interleave beats all-loads-then-compute)
//   - TLP (R4: 2x waves/SIMD vs R2 -> 0 change)
//   - merged 1-block/CU (R3: -18%, lost cross-block drain overlap)
//   - counted-vmcnt triple-buffer, no vmcnt(0) drain (R7: 0 change)
//   - 3-phase column-split, fewer LDS bytes + more barriers (R8: -60%)
//   - bf16 / f16+fma_mix weights (R9/R10: LDS<->VALU product conserved, worse)
//   - W3/W1 off-LDS to per-wave global reads (R11: L2 replication, worse)
// Floor: ~127us = 80 serialized steps x {9-row L2->LDS multicast + whole-CU
// barrier + cross-wave broadcast chain}; all pipes individually sub-saturated.
__global__ __launch_bounds__(512, 4) void made_sample(
    const float* __restrict__ ctx,   // (B, C)
    const float* __restrict__ eps,   // (B, D)
    const float* __restrict__ W1,    // (D+C, H)
    const float* __restrict__ b1,    // (H)
    const float* __restrict__ W2,    // (H, H)
    const float* __restrict__ b2,    // (H)
    const float* __restrict__ W3,    // (H, 2D)
    const float* __restrict__ b3,    // (2D)
    float* __restrict__ out)         // (B, D)
{
    const int lane  = threadIdx.x & 63;
    const int w     = threadIdx.x >> 6;          // wave 0..7
    const int rrow  = blockIdx.x * 8 + w;        // 1 batch row per wave
    const int jbase = 8 * lane;

    __shared__ float sbuf[2][10 * HH];           // 2 x 20 KB (slots: 9 W2 + 1 W1)
    __shared__ float w3sb[2][5 * 256];           // 2 x 5 KB  (5 pairs of W3 rows)

    int deg[8];
    #pragma unroll
    for (int u = 0; u < 8; ++u) deg[u] = (jbase + u) % 63 + 1;

    // split-half LDS read: slot base -> 4 f32x2 (8 floats) for this lane
    auto load8v = [&](const float* base_, f32x2* r_) {
        float4 a = *(const float4*)(base_ + lane * 4);
        float4 b = *(const float4*)(base_ + 256 + lane * 4);
        r_[0][0] = a.x; r_[0][1] = a.y; r_[1][0] = a.z; r_[1][1] = a.w;
        r_[2][0] = b.x; r_[2][1] = b.y; r_[3][0] = b.z; r_[3][1] = b.w;
    };
    auto stage_row = [&](const float* src, float* dst) {
        glds16(src + lane * 8,     dst);
        glds16(src + lane * 8 + 4, dst + 256);
    };
    // stage W3 rows k0,k1 (128 floats each) into one 1KB pair slot:
    // lanes 0..31 carry row k0 (bytes 0..511), lanes 32..63 row k1 (512..1023).
    auto stage_w3pair = [&](int k0, int k1, float* dst) {
        const float* g = (lane < 32) ? (W3 + k0 * (2 * DD) + lane * 4)
                                     : (W3 + k1 * (2 * DD) + (lane - 32) * 4);
        glds16(g, dst);
    };

    f32x2 p1[4], p2[4], acc;
    #pragma unroll
    for (int j = 0; j < 4; ++j) {
        p1[j][0] = b1[jbase + 2 * j]; p1[j][1] = b1[jbase + 2 * j + 1];
        p2[j][0] = b2[jbase + 2 * j]; p2[j][1] = b2[jbase + 2 * j + 1];
    }
    acc = splat2(0.f);

    const float ca = ctx[rrow * CC + lane];
    const float cb = ctx[rrow * CC + 64 + lane];
    const float ep = eps[rrow * DD + lane];
    const float b3m = b3[lane];        // bias for mean col `lane`
    const float b3p = b3[64 + lane];   // bias for prescale col `lane`

    // ctx chunk ch: W1 rows DD+8ch..DD+8ch+7 -> slots 0..7 (1 row per wave)
    auto stage_ctx = [&](int ch, float* buf) {
        stage_row(W1 + (DD + 8 * ch + w) * HH, buf + w * HH);
    };
    // staging for main step `in`, spread over 8 waves:
    //   wave w (0..7): W2 row basen+63*w -> slot w
    //   wave 0: + W2 row basen+504 -> slot 8      (iff basen<8)
    //   wave 1: + W1 row `in` -> slot 9
    //   waves 2..5: W3 pair p=w-2 (rows basen+63*2p, basen+63*(2p+1))
    //   wave 6: W3 pair 4 (row basen+504 dup)     (iff basen<8)
    auto stage_step = [&](int in, float* buf, float* w3buf) {
        if (in == 0) {                       // step 0 needs only W1 row 0
            if (w == 1) stage_row(W1, buf + 9 * HH);
            return;
        }
        const int basen = in - 1;
        const bool h9n = basen < 8;
        stage_row(W2 + (basen + 63 * w) * HH, buf + w * HH);
        if (w == 0 && h9n) stage_row(W2 + (basen + 504) * HH, buf + 8 * HH);
        if (w == 1) stage_row(W1 + in * HH, buf + 9 * HH);
        if (w >= 2 && w <= 5) {
            const int p = w - 2;
            stage_w3pair(basen + 63 * (2 * p), basen + 63 * (2 * p + 1),
                         w3buf + p * 256);
        }
        if (w == 6 && h9n)
            stage_w3pair(basen + 504, basen + 504, w3buf + 4 * 256);
    };

    // ---- context init: pre1 += ctx @ W1[D:,:], 16 chunks of 8 rows ----
    stage_ctx(0, sbuf[0]);
    __syncthreads();
    #pragma unroll 1
    for (int ch = 0; ch < 16; ++ch) {
        float* cur = sbuf[ch & 1];
        if (ch < 15) stage_ctx(ch + 1, sbuf[(ch + 1) & 1]);
        else         stage_step(0, sbuf[0], w3sb[0]);   // (16)&1==0: parity OK
        #pragma unroll
        for (int q = 0; q < 8; ++q) {
            f32x2 cw[4];
            load8v(cur + q * HH, cw);
            const int c = 8 * ch + q;
            const u64 cvp = rl_pair((ch < 8) ? ca : cb, c & 63);
            #pragma unroll
            for (int j = 0; j < 4; ++j) p1[j] = pk_fma_s(cvp, cw[j], p1[j]);
        }
        __syncthreads();
    }

    float z = 0.f;

    // ---- autoregressive main loop ----
    #pragma unroll 1
    for (int i = 0; i < DD; ++i) {
        float* cur = sbuf[i & 1];
        const float* w3s = w3sb[i & 1];

        // issue next-step staging first (vmcnt countdown starts earliest)
        if (i < 63) stage_step(i + 1, sbuf[(i + 1) & 1], w3sb[(i + 1) & 1]);

        f32x2 w1v[4];
        load8v(cur + 9 * HH, w1v);

        if (i > 0) {                      // i==0: no unit has deg==0, all h==0
            const int base = i - 1;
            const bool h9 = base < 8;     // 9th finalizing unit exists (i<=8)

            // (a) select finalized h1 (deg==i)
            float m0 = 0.f;
            #pragma unroll
            for (int u = 0; u < 8; ++u)
                m0 = (deg[u] == i) ? p1[u >> 1][u & 1] : m0;
            m0 = fmaxf(m0, 0.f);

            // (b) rank update of pre2 (packed FMA, SGPR-pair h operand)
            #pragma unroll
            for (int t = 0; t < 8; ++t) {
                const int k = base + 63 * t;
                f32x2 wv[4];
                load8v(cur + t * HH, wv);
                const u64 h0 = rl_pair(m0, k >> 3);
                #pragma unroll
                for (int j = 0; j < 4; ++j) p2[j] = pk_fma_s(h0, wv[j], p2[j]);
            }
            if (h9) {                     // t=8: unit base+504, owner lane 63
                f32x2 wv[4];
                load8v(cur + 8 * HH, wv);
                const u64 h0 = rl_pair(m0, 63);
                #pragma unroll
                for (int j = 0; j < 4; ++j) p2[j] = pk_fma_s(h0, wv[j], p2[j]);
            }

            // (c) capture newly-final h2 (deg==i)
            float g0 = 0.f;
            #pragma unroll
            for (int u = 0; u < 8; ++u)
                g0 = (deg[u] == i) ? p2[u >> 1][u & 1] : g0;
            g0 = fmaxf(g0, 0.f);

            // (d) incremental W3 accumulation (scalar v_fmac, SGPR h operand)
            #pragma unroll
            for (int t = 0; t < 8; ++t) {
                const int k = base + 63 * t;
                const float wa = w3s[t * 128 + lane];        // W3[k, lane]
                const float wb = w3s[t * 128 + 64 + lane];   // W3[k, 64+lane]
                const float h0 = bcast(g0, k >> 3);
                acc[0] = fmaf(h0, wa, acc[0]);
                acc[1] = fmaf(h0, wb, acc[1]);
            }
            if (h9) {
                const float wa = w3s[8 * 128 + lane];
                const float wb = w3s[8 * 128 + 64 + lane];
                const float h0 = bcast(g0, 63);
                acc[0] = fmaf(h0, wa, acc[0]);
                acc[1] = fmaf(h0, wb, acc[1]);
            }
        }

        // (e) z_i: column i's totals live in lane i; every lane computes its
        // own candidate (parallel), one readlane extracts; feed back into p1.
        {
            const float am = acc[0] + b3m;
            const float ap = acc[1] + b3p;
            const float sp = fast_softplus(ap);
            const float zc = fmaf(sp, ep, am);
            if (lane == i) z = bcast(zc, i);
            const u64 zp = rl_pair(zc, i);
            #pragma unroll
            for (int j = 0; j < 4; ++j) p1[j] = pk_fma_s(zp, w1v[j], p1[j]);
        }

        __syncthreads();
    }

    out[rrow * DD + lane] = z;
}

extern "C" void kernel_launch(void* const* d_in, const int* in_sizes, int n_in,
                              void* d_out, int out_size, void* d_ws, size_t ws_size,
                              hipStream_t stream) {
    const float* ctx = (const float*)d_in[0];
    const float* eps = (const float*)d_in[1];
    const float* W1  = (const float*)d_in[2];
    const float* b1  = (const float*)d_in[3];
    const float* W2  = (const float*)d_in[4];
    const float* b2  = (const float*)d_in[5];
    const float* W3  = (const float*)d_in[6];
    const float* b3  = (const float*)d_in[7];
    (void)d_ws; (void)ws_size; (void)in_sizes; (void)n_in; (void)out_size;

    made_sample<<<BATCH / 8, 512, 0, stream>>>(ctx, eps, W1, b1, W2, b2, W3, b3,
                                               (float*)d_out);
}